// Round 1
// baseline (710.881 us; speedup 1.0000x reference)
//
#include <hip/hip_runtime.h>
#include <math.h>

#define NNODES 10000
#define NEDGES 160000
#define FIN    256
#define HIDC   128
#define NH1    5
#define NH3    3
#define NCLS   10
#define NG     64

__device__ __forceinline__ float wave_sum(float v) {
    #pragma unroll
    for (int m = 32; m; m >>= 1) v += __shfl_xor(v, m);
    return v;
}
__device__ __forceinline__ float wave_max(float v) {
    #pragma unroll
    for (int m = 32; m; m >>= 1) v = fmaxf(v, __shfl_xor(v, m));
    return v;
}

// ---------------- CSR build ----------------
__global__ void k_init(int* __restrict__ deg, int* __restrict__ cursor, int n) {
    int i = blockIdx.x * blockDim.x + threadIdx.x;
    if (i < n) { deg[i] = 1; cursor[i] = 0; }   // deg starts at 1: self-loop
}

__global__ void k_count(const int* __restrict__ dstv, int* __restrict__ deg, int E) {
    int e = blockIdx.x * blockDim.x + threadIdx.x;
    if (e < E) atomicAdd(&deg[dstv[e]], 1);
}

// single-block exclusive scan: offs[0]=0, offs[i+1]=sum(deg[0..i])
__global__ void k_scan(const int* __restrict__ deg, int* __restrict__ offs, int n) {
    __shared__ int wsum[4];
    __shared__ int carry_s;
    const int lane = threadIdx.x & 63, wave = threadIdx.x >> 6;
    if (threadIdx.x == 0) carry_s = 0;
    __syncthreads();
    for (int base = 0; base < n; base += 256) {
        int i = base + (int)threadIdx.x;
        int v = (i < n) ? deg[i] : 0;
        int xs = v;
        #pragma unroll
        for (int d = 1; d < 64; d <<= 1) {
            int y = __shfl_up(xs, d);
            if (lane >= d) xs += y;
        }
        if (lane == 63) wsum[wave] = xs;
        __syncthreads();
        int wadd = 0;
        for (int w = 0; w < wave; ++w) wadd += wsum[w];
        int incl = carry_s + wadd + xs;
        if (i < n) offs[i + 1] = incl;
        __syncthreads();
        if (threadIdx.x == 255) carry_s = incl;
        __syncthreads();
    }
    if (threadIdx.x == 0) offs[0] = 0;
}

__global__ void k_scatter(const int* __restrict__ srcv, const int* __restrict__ dstv,
                          const int* __restrict__ offs, int* __restrict__ cursor,
                          int* __restrict__ csr, int E, int N) {
    int e = blockIdx.x * blockDim.x + threadIdx.x;
    if (e >= E + N) return;
    int s, d;
    if (e < E) { s = srcv[e]; d = dstv[e]; }
    else       { s = d = e - E; }                 // self-loop
    int pos = offs[d] + atomicAdd(&cursor[d], 1);
    csr[pos] = s;
}

// ---------------- fp32 tiled GEMM: C[M,Nw] = A[M,K] @ B[K,Nw] ----------------
// 64x64 tile, 256 threads, 4x4 per thread, Ktile=16. K,Nw multiples of 16/64.
__global__ __launch_bounds__(256) void k_gemm(const float* __restrict__ A,
                                              const float* __restrict__ B,
                                              float* __restrict__ C,
                                              int M, int K, int Nw) {
    __shared__ float As[16][68];
    __shared__ float Bs[16][68];
    const int t  = threadIdx.x;
    const int tx = t & 15, ty = t >> 4;
    const int row0 = blockIdx.x * 64, col0 = blockIdx.y * 64;
    const int am = t >> 2, ak = (t & 3) * 4;   // A: 64 rows x 16 k, float4 per thread
    const int bn = t & 63, bk = (t >> 6) * 4;  // B: 16 k x 64 n, 4 rows per thread
    float acc[4][4] = {};
    for (int k0 = 0; k0 < K; k0 += 16) {
        float4 av = make_float4(0.f, 0.f, 0.f, 0.f);
        int arow = row0 + am;
        if (arow < M)
            av = *reinterpret_cast<const float4*>(A + (size_t)arow * K + k0 + ak);
        As[ak + 0][am] = av.x; As[ak + 1][am] = av.y;
        As[ak + 2][am] = av.z; As[ak + 3][am] = av.w;
        #pragma unroll
        for (int j = 0; j < 4; ++j)
            Bs[bk + j][bn] = B[(size_t)(k0 + bk + j) * Nw + col0 + bn];
        __syncthreads();
        #pragma unroll
        for (int k = 0; k < 16; ++k) {
            float a[4], b[4];
            #pragma unroll
            for (int i = 0; i < 4; ++i) a[i] = As[k][ty * 4 + i];
            #pragma unroll
            for (int j = 0; j < 4; ++j) b[j] = Bs[k][tx * 4 + j];
            #pragma unroll
            for (int i = 0; i < 4; ++i)
                #pragma unroll
                for (int j = 0; j < 4; ++j)
                    acc[i][j] = fmaf(a[i], b[j], acc[i][j]);
        }
        __syncthreads();
    }
    #pragma unroll
    for (int i = 0; i < 4; ++i) {
        int r = row0 + ty * 4 + i;
        if (r < M) {
            #pragma unroll
            for (int j = 0; j < 4; ++j)
                C[(size_t)r * Nw + col0 + tx * 4 + j] = acc[i][j];
        }
    }
}

// ---------------- attention coefficients: als/ald[n,h] = dot(h[n,h,:], a[h,:]) ----------------
__global__ void k_alphas(const float* __restrict__ h, const float* __restrict__ a_s,
                         const float* __restrict__ a_d, float* __restrict__ als,
                         float* __restrict__ ald, int NHtot, int H) {
    int wid  = (blockIdx.x * blockDim.x + threadIdx.x) >> 6;
    int lane = threadIdx.x & 63;
    if (wid >= NHtot) return;
    int head = wid % H;
    const float* hp = h + (size_t)wid * HIDC;
    const float* asp = a_s + head * HIDC;
    const float* adp = a_d + head * HIDC;
    float h0 = hp[lane], h1 = hp[lane + 64];
    float s1 = h0 * asp[lane] + h1 * asp[lane + 64];
    float s2 = h0 * adp[lane] + h1 * adp[lane + 64];
    s1 = wave_sum(s1);
    s2 = wave_sum(s2);
    if (lane == 0) { als[wid] = s1; ald[wid] = s2; }
}

// ---------------- softmax + aggregate: one wave per (node, head) ----------------
__global__ __launch_bounds__(64) void k_agg(const float* __restrict__ h,
                                            const float* __restrict__ als,
                                            const float* __restrict__ ald,
                                            const int* __restrict__ offs,
                                            const int* __restrict__ csr,
                                            float* __restrict__ agg, int H) {
    const int b = blockIdx.x;          // n*H + head
    const int n = b / H, head = b % H;
    const int lane = threadIdx.x;
    const int e0 = offs[n], e1 = offs[n + 1];
    const float aldn = ald[(size_t)n * H + head];
    // pass 1: max logit
    float m = -1e30f;
    for (int e = e0 + lane; e < e1; e += 64) {
        int s = csr[e];
        float v = als[(size_t)s * H + head] + aldn;
        v = v > 0.f ? v : 0.2f * v;
        m = fmaxf(m, v);
    }
    m = wave_max(m);
    // pass 2: sum of exp
    float ssum = 0.f;
    for (int e = e0 + lane; e < e1; e += 64) {
        int s = csr[e];
        float v = als[(size_t)s * H + head] + aldn;
        v = v > 0.f ? v : 0.2f * v;
        ssum += __expf(v - m);
    }
    ssum = wave_sum(ssum);
    const float inv = 1.f / (ssum + 1e-16f);
    // pass 3: weighted aggregation, 2 features per lane
    float acc0 = 0.f, acc1 = 0.f;
    for (int e = e0; e < e1; ++e) {
        int s = csr[e];                               // wave-uniform broadcast load
        float v = als[(size_t)s * H + head] + aldn;
        v = v > 0.f ? v : 0.2f * v;
        float w = __expf(v - m);
        const float* hp = h + ((size_t)s * H + head) * HIDC;
        acc0 = fmaf(w, hp[lane], acc0);
        acc1 = fmaf(w, hp[lane + 64], acc1);
    }
    float* op = agg + ((size_t)n * H + head) * HIDC;
    op[lane]      = acc0 * inv;
    op[lane + 64] = acc1 * inv;
}

// ---------------- epilogues ----------------
__global__ void k_elu_bias(const float* __restrict__ agg, const float* __restrict__ b,
                           float* __restrict__ o, int total, int Fw) {
    int i = blockIdx.x * blockDim.x + threadIdx.x;
    if (i >= total) return;
    float v = agg[i] + b[i % Fw];
    o[i] = v > 0.f ? v : expm1f(v);
}

__global__ void k_res_elu_bias(const float* __restrict__ xr, const float* __restrict__ agg,
                               const float* __restrict__ b, float* __restrict__ o,
                               int total, int Fw) {
    int i = blockIdx.x * blockDim.x + threadIdx.x;
    if (i >= total) return;
    float v = xr[i] + agg[i] + b[i % Fw];
    o[i] = v > 0.f ? v : expm1f(v);
}

__global__ void k_mean_bias(const float* __restrict__ agg, const float* __restrict__ b,
                            float* __restrict__ o, int total) {
    int i = blockIdx.x * blockDim.x + threadIdx.x;
    if (i >= total) return;
    int n = i >> 7, c = i & 127;
    float v = (agg[((size_t)n * 3 + 0) * HIDC + c] +
               agg[((size_t)n * 3 + 1) * HIDC + c] +
               agg[((size_t)n * 3 + 2) * HIDC + c]) * (1.f / 3.f) + b[c];
    o[i] = v;
}

// ---------------- pooling + head ----------------
__global__ void k_pool_zero(float* __restrict__ pooled, float* __restrict__ cnts) {
    int i = blockIdx.x * blockDim.x + threadIdx.x;
    if (i < NG * HIDC) pooled[i] = 0.f;
    if (i < NG) cnts[i] = 0.f;
}

__global__ void k_pool_add(const float* __restrict__ x3, const int* __restrict__ batch,
                           float* __restrict__ pooled, float* __restrict__ cnts, int N) {
    int i = blockIdx.x * blockDim.x + threadIdx.x;
    if (i >= N * HIDC) return;
    int n = i >> 7, c = i & 127;
    int g = batch[n];
    atomicAdd(&pooled[g * HIDC + c], x3[i]);
    if (c == 0) atomicAdd(&cnts[g], 1.0f);
}

__global__ void k_head(const float* __restrict__ pooled, const float* __restrict__ cnts,
                       const float* __restrict__ Wc, const float* __restrict__ bc,
                       float* __restrict__ out) {
    __shared__ float lg[NG][NCLS];
    int tid = threadIdx.x;
    if (tid < NG * NCLS) {
        int g = tid / NCLS, c = tid % NCLS;
        float invc = 1.f / fmaxf(cnts[g], 1.f);
        float s = bc[c];
        for (int k = 0; k < HIDC; ++k)
            s = fmaf(pooled[g * HIDC + k] * invc, Wc[k * NCLS + c], s);
        lg[g][c] = s;
        out[tid] = s;                 // logits
    }
    __syncthreads();
    if (tid < NG * NCLS) {
        int g = tid / NCLS, c = tid % NCLS;
        float m = -1e30f;
        for (int j = 0; j < NCLS; ++j) m = fmaxf(m, lg[g][j]);
        float se = 0.f;
        for (int j = 0; j < NCLS; ++j) se += __expf(lg[g][j] - m);
        out[NG * NCLS + tid] = lg[g][c] - m - __logf(se);
    }
}

extern "C" void kernel_launch(void* const* d_in, const int* in_sizes, int n_in,
                              void* d_out, int out_size, void* d_ws, size_t ws_size,
                              hipStream_t stream) {
    const float* x   = (const float*)d_in[0];
    const int*   ei  = (const int*)d_in[1];
    const int*   bat = (const int*)d_in[2];
    const float* W1  = (const float*)d_in[3];
    const float* a1s = (const float*)d_in[4];
    const float* a1d = (const float*)d_in[5];
    const float* b1  = (const float*)d_in[6];
    const float* W2  = (const float*)d_in[7];
    const float* a2s = (const float*)d_in[8];
    const float* a2d = (const float*)d_in[9];
    const float* b2  = (const float*)d_in[10];
    const float* W3  = (const float*)d_in[11];
    const float* a3s = (const float*)d_in[12];
    const float* a3d = (const float*)d_in[13];
    const float* b3  = (const float*)d_in[14];
    const float* Wc  = (const float*)d_in[15];
    const float* bc  = (const float*)d_in[16];
    float* out = (float*)d_out;

    char* p = (char*)d_ws;
    auto alloc = [&](size_t bytes) -> char* {
        char* r = p; p += (bytes + 255) & ~(size_t)255; return r;
    };
    float* h      = (float*)alloc((size_t)NNODES * 640 * 4);
    float* agg    = (float*)alloc((size_t)NNODES * 640 * 4);
    float* x1     = (float*)alloc((size_t)NNODES * 640 * 4);
    float* x2     = (float*)alloc((size_t)NNODES * 640 * 4);
    float* x3     = (float*)alloc((size_t)NNODES * HIDC * 4);
    float* als    = (float*)alloc((size_t)NNODES * NH1 * 4);
    float* ald    = (float*)alloc((size_t)NNODES * NH1 * 4);
    float* pooled = (float*)alloc(NG * HIDC * 4);
    float* cnts   = (float*)alloc(NG * 4);
    int*   offs   = (int*)alloc((NNODES + 1) * 4);
    int*   cursor = (int*)alloc(NNODES * 4);
    int*   deg    = (int*)alloc(NNODES * 4);
    int*   csr    = (int*)alloc((size_t)(NEDGES + NNODES) * 4);

    const int* srcv = ei;
    const int* dstv = ei + NEDGES;

    // CSR by destination (self-loops included)
    k_init<<<(NNODES + 255) / 256, 256, 0, stream>>>(deg, cursor, NNODES);
    k_count<<<(NEDGES + 255) / 256, 256, 0, stream>>>(dstv, deg, NEDGES);
    k_scan<<<1, 256, 0, stream>>>(deg, offs, NNODES);
    k_scatter<<<(NEDGES + NNODES + 255) / 256, 256, 0, stream>>>(srcv, dstv, offs, cursor,
                                                                 csr, NEDGES, NNODES);

    const int MB = (NNODES + 63) / 64;   // 157

    // ---- layer 1 ----
    k_gemm<<<dim3(MB, 10), 256, 0, stream>>>(x, W1, h, NNODES, FIN, 640);
    k_alphas<<<(NNODES * NH1 + 3) / 4, 256, 0, stream>>>(h, a1s, a1d, als, ald,
                                                         NNODES * NH1, NH1);
    k_agg<<<NNODES * NH1, 64, 0, stream>>>(h, als, ald, offs, csr, agg, NH1);
    k_elu_bias<<<(NNODES * 640 + 255) / 256, 256, 0, stream>>>(agg, b1, x1,
                                                               NNODES * 640, 640);
    // ---- layer 2 ----
    k_gemm<<<dim3(MB, 10), 256, 0, stream>>>(x1, W2, h, NNODES, 640, 640);
    k_alphas<<<(NNODES * NH1 + 3) / 4, 256, 0, stream>>>(h, a2s, a2d, als, ald,
                                                         NNODES * NH1, NH1);
    k_agg<<<NNODES * NH1, 64, 0, stream>>>(h, als, ald, offs, csr, agg, NH1);
    k_res_elu_bias<<<(NNODES * 640 + 255) / 256, 256, 0, stream>>>(x1, agg, b2, x2,
                                                                   NNODES * 640, 640);
    // ---- layer 3 ----
    k_gemm<<<dim3(MB, 6), 256, 0, stream>>>(x2, W3, h, NNODES, 640, 384);
    k_alphas<<<(NNODES * NH3 + 3) / 4, 256, 0, stream>>>(h, a3s, a3d, als, ald,
                                                         NNODES * NH3, NH3);
    k_agg<<<NNODES * NH3, 64, 0, stream>>>(h, als, ald, offs, csr, agg, NH3);
    k_mean_bias<<<(NNODES * HIDC + 255) / 256, 256, 0, stream>>>(agg, b3, x3,
                                                                 NNODES * HIDC);
    // ---- pool + head ----
    k_pool_zero<<<(NG * HIDC + 255) / 256, 256, 0, stream>>>(pooled, cnts);
    k_pool_add<<<(NNODES * HIDC + 255) / 256, 256, 0, stream>>>(x3, bat, pooled, cnts,
                                                                NNODES);
    k_head<<<1, 640, 0, stream>>>(pooled, cnts, Wc, bc, out);
}

// Round 2
// 517.353 us; speedup vs baseline: 1.3741x; 1.3741x over previous
//
#include <hip/hip_runtime.h>
#include <math.h>

#define NNODES 10000
#define NPAD   10112          // 79 * 128
#define NEDGES 160000
#define FIN    256
#define HIDC   128
#define NH1    5
#define NH3    3
#define NCLS   10
#define NG     64

typedef unsigned short u16;
typedef unsigned int   u32;
typedef __attribute__((ext_vector_type(8))) short short8;
typedef __attribute__((ext_vector_type(4))) float f32x4;

__device__ __forceinline__ u16 f2b(float f) {
    union { float f; u32 u; } v; v.f = f;
    u32 r = v.u + 0x7FFF + ((v.u >> 16) & 1);   // RNE
    return (u16)(r >> 16);
}
__device__ __forceinline__ float b2f(u16 b) {
    union { u32 u; float f; } v; v.u = ((u32)b) << 16; return v.f;
}

__device__ __forceinline__ float wave_sum(float v) {
    #pragma unroll
    for (int m = 32; m; m >>= 1) v += __shfl_xor(v, m);
    return v;
}
__device__ __forceinline__ float wave_max(float v) {
    #pragma unroll
    for (int m = 32; m; m >>= 1) v = fmaxf(v, __shfl_xor(v, m));
    return v;
}

// ---------------- CSR build ----------------
__global__ void k_init(int* __restrict__ deg, int* __restrict__ cursor, int n) {
    int i = blockIdx.x * blockDim.x + threadIdx.x;
    if (i < n) { deg[i] = 1; cursor[i] = 0; }   // deg starts at 1: self-loop
}

__global__ void k_count(const int* __restrict__ dstv, int* __restrict__ deg, int E) {
    int e = blockIdx.x * blockDim.x + threadIdx.x;
    if (e < E) atomicAdd(&deg[dstv[e]], 1);
}

__global__ void k_scan(const int* __restrict__ deg, int* __restrict__ offs, int n) {
    __shared__ int wsum[4];
    __shared__ int carry_s;
    const int lane = threadIdx.x & 63, wave = threadIdx.x >> 6;
    if (threadIdx.x == 0) carry_s = 0;
    __syncthreads();
    for (int base = 0; base < n; base += 256) {
        int i = base + (int)threadIdx.x;
        int v = (i < n) ? deg[i] : 0;
        int xs = v;
        #pragma unroll
        for (int d = 1; d < 64; d <<= 1) {
            int y = __shfl_up(xs, d);
            if (lane >= d) xs += y;
        }
        if (lane == 63) wsum[wave] = xs;
        __syncthreads();
        int wadd = 0;
        for (int w = 0; w < wave; ++w) wadd += wsum[w];
        int incl = carry_s + wadd + xs;
        if (i < n) offs[i + 1] = incl;
        __syncthreads();
        if (threadIdx.x == 255) carry_s = incl;
        __syncthreads();
    }
    if (threadIdx.x == 0) offs[0] = 0;
}

__global__ void k_scatter(const int* __restrict__ srcv, const int* __restrict__ dstv,
                          const int* __restrict__ offs, int* __restrict__ cursor,
                          int* __restrict__ csr, int E, int N) {
    int e = blockIdx.x * blockDim.x + threadIdx.x;
    if (e >= E + N) return;
    int s, d;
    if (e < E) { s = srcv[e]; d = dstv[e]; }
    else       { s = d = e - E; }                 // self-loop
    int pos = offs[d] + atomicAdd(&cursor[d], 1);
    csr[pos] = s;
}

// ---------------- fp32 -> bf16 conversions ----------------
__global__ void k_f2b4(const float4* __restrict__ X, uint2* __restrict__ Y, int n4) {
    int i = blockIdx.x * blockDim.x + threadIdx.x;
    if (i >= n4) return;
    float4 v = X[i];
    uint2 o;
    o.x = (u32)f2b(v.x) | ((u32)f2b(v.y) << 16);
    o.y = (u32)f2b(v.z) | ((u32)f2b(v.w) << 16);
    Y[i] = o;
}

// W[K][Nw] fp32 -> Wt[Nw][K] bf16
__global__ void k_wt(const float* __restrict__ W, u16* __restrict__ Wt, int K, int Nw) {
    int i = blockIdx.x * blockDim.x + threadIdx.x;
    if (i >= K * Nw) return;
    int k = i / Nw, n = i - k * Nw;
    Wt[(size_t)n * K + k] = f2b(W[i]);
}

// ---------------- bf16 MFMA GEMM: C[M][Nw] = A[Mpad][K] @ Bt[Nw][K]^T ----------------
// 128x128 block tile, BK=64, 4 waves, each wave 4x4 frags of 16x16x32 MFMA.
// LDS layout [row][64] with XOR swizzle on 8-element k-groups to avoid bank conflicts.
__global__ __launch_bounds__(256) void k_gemm_mfma(const u16* __restrict__ A,
                                                   const u16* __restrict__ Bt,
                                                   u16* __restrict__ C,
                                                   int M, int K, int Nw) {
    __shared__ __align__(16) u16 As[128 * 64];
    __shared__ __align__(16) u16 Bs[128 * 64];
    const int t = threadIdx.x;
    const int lane = t & 63, wave = t >> 6;
    const int row0 = blockIdx.x * 128, col0 = blockIdx.y * 128;
    const int wm = (wave >> 1) * 64, wn = (wave & 1) * 64;
    const int frow = lane & 15, quad = lane >> 4;

    f32x4 acc[4][4];
    #pragma unroll
    for (int i = 0; i < 4; ++i)
        #pragma unroll
        for (int j = 0; j < 4; ++j)
            acc[i][j] = (f32x4){0.f, 0.f, 0.f, 0.f};

    // staging: thread t loads 4 x 16B for A and 4 x 16B for B per K-step
    const int srow = t >> 3;            // 0..31 (row within 32-row stripe)
    const int sg   = t & 7;             // k-group 0..7 (8 bf16 each)

    for (int k0 = 0; k0 < K; k0 += 64) {
        short8 avec[4], bvec[4];
        #pragma unroll
        for (int i = 0; i < 4; ++i) {
            int r = srow + i * 32;
            avec[i] = *(const short8*)(A  + (size_t)(row0 + r) * K + k0 + sg * 8);
            bvec[i] = *(const short8*)(Bt + (size_t)(col0 + r) * K + k0 + sg * 8);
        }
        __syncthreads();   // previous compute done before overwriting LDS
        #pragma unroll
        for (int i = 0; i < 4; ++i) {
            int r = srow + i * 32;
            int gsw = (sg ^ (r & 7)) * 8;
            *(short8*)(As + r * 64 + gsw) = avec[i];
            *(short8*)(Bs + r * 64 + gsw) = bvec[i];
        }
        __syncthreads();
        #pragma unroll
        for (int c = 0; c < 2; ++c) {
            short8 af[4], bfv[4];
            #pragma unroll
            for (int mi = 0; mi < 4; ++mi) {
                int rr = wm + mi * 16 + frow;
                int g = (c * 4 + quad) ^ (rr & 7);
                af[mi] = *(const short8*)(As + rr * 64 + g * 8);
            }
            #pragma unroll
            for (int ni = 0; ni < 4; ++ni) {
                int rr = wn + ni * 16 + frow;
                int g = (c * 4 + quad) ^ (rr & 7);
                bfv[ni] = *(const short8*)(Bs + rr * 64 + g * 8);
            }
            #pragma unroll
            for (int mi = 0; mi < 4; ++mi)
                #pragma unroll
                for (int ni = 0; ni < 4; ++ni)
                    acc[mi][ni] = __builtin_amdgcn_mfma_f32_16x16x32_bf16(
                        af[mi], bfv[ni], acc[mi][ni], 0, 0, 0);
        }
    }
    // epilogue: C/D layout col=lane&15, row=quad*4+r ; store bf16
    #pragma unroll
    for (int mi = 0; mi < 4; ++mi) {
        #pragma unroll
        for (int r = 0; r < 4; ++r) {
            int row = row0 + wm + mi * 16 + quad * 4 + r;
            if (row < M) {
                #pragma unroll
                for (int ni = 0; ni < 4; ++ni) {
                    int col = col0 + wn + ni * 16 + frow;
                    C[(size_t)row * Nw + col] = f2b(acc[mi][ni][r]);
                }
            }
        }
    }
}

// ---------------- attention coefficients from bf16 h ----------------
__global__ void k_alphas(const u16* __restrict__ h, const float* __restrict__ a_s,
                         const float* __restrict__ a_d, float* __restrict__ als,
                         float* __restrict__ ald, int NHtot, int H) {
    int wid  = (blockIdx.x * blockDim.x + threadIdx.x) >> 6;
    int lane = threadIdx.x & 63;
    if (wid >= NHtot) return;
    int head = wid % H;
    const u16* hp = h + (size_t)wid * HIDC;
    const float* asp = a_s + head * HIDC;
    const float* adp = a_d + head * HIDC;
    float h0 = b2f(hp[lane]), h1 = b2f(hp[lane + 64]);
    float s1 = h0 * asp[lane] + h1 * asp[lane + 64];
    float s2 = h0 * adp[lane] + h1 * adp[lane + 64];
    s1 = wave_sum(s1);
    s2 = wave_sum(s2);
    if (lane == 0) { als[wid] = s1; ald[wid] = s2; }
}

// ---------------- softmax + aggregate: one wave per (node, head), bf16 h ----------------
__global__ __launch_bounds__(64) void k_agg(const u16* __restrict__ h,
                                            const float* __restrict__ als,
                                            const float* __restrict__ ald,
                                            const int* __restrict__ offs,
                                            const int* __restrict__ csr,
                                            float* __restrict__ agg, int H) {
    const int b = blockIdx.x;          // n*H + head
    const int n = b / H, head = b % H;
    const int lane = threadIdx.x;
    const int e0 = offs[n], e1 = offs[n + 1];
    const float aldn = ald[(size_t)n * H + head];
    float m = -1e30f;
    for (int e = e0 + lane; e < e1; e += 64) {
        int s = csr[e];
        float v = als[(size_t)s * H + head] + aldn;
        v = v > 0.f ? v : 0.2f * v;
        m = fmaxf(m, v);
    }
    m = wave_max(m);
    float ssum = 0.f;
    for (int e = e0 + lane; e < e1; e += 64) {
        int s = csr[e];
        float v = als[(size_t)s * H + head] + aldn;
        v = v > 0.f ? v : 0.2f * v;
        ssum += __expf(v - m);
    }
    ssum = wave_sum(ssum);
    const float inv = 1.f / (ssum + 1e-16f);
    // lane handles features 2*lane, 2*lane+1 (one 4B bf16-pair load per lane)
    float acc0 = 0.f, acc1 = 0.f;
    for (int e = e0; e < e1; ++e) {
        int s = csr[e];                               // wave-uniform broadcast load
        float v = als[(size_t)s * H + head] + aldn;
        v = v > 0.f ? v : 0.2f * v;
        float w = __expf(v - m);
        const u16* hp = h + ((size_t)s * H + head) * HIDC;
        u32 pr = *(const u32*)(hp + 2 * lane);
        acc0 = fmaf(w, b2f((u16)(pr & 0xffff)), acc0);
        acc1 = fmaf(w, b2f((u16)(pr >> 16)), acc1);
    }
    float* op = agg + ((size_t)n * H + head) * HIDC;
    *(float2*)(op + 2 * lane) = make_float2(acc0 * inv, acc1 * inv);
}

// ---------------- epilogues ----------------
// x1 = elu(agg+b) -> fp32 (for residual) + bf16 (next GEMM A)
__global__ void k_elu_bias2(const float* __restrict__ agg, const float* __restrict__ b,
                            float* __restrict__ o, u16* __restrict__ obf,
                            int total, int Fw) {
    int i = blockIdx.x * blockDim.x + threadIdx.x;
    if (i >= total) return;
    float v = agg[i] + b[i % Fw];
    v = v > 0.f ? v : expm1f(v);
    o[i] = v;
    obf[i] = f2b(v);
}

// x2 = elu(x1 + agg + b) -> bf16 only (feeds GEMM3)
__global__ void k_res_elu_bias(const float* __restrict__ xr, const float* __restrict__ agg,
                               const float* __restrict__ b, u16* __restrict__ obf,
                               int total, int Fw) {
    int i = blockIdx.x * blockDim.x + threadIdx.x;
    if (i >= total) return;
    float v = xr[i] + agg[i] + b[i % Fw];
    v = v > 0.f ? v : expm1f(v);
    obf[i] = f2b(v);
}

__global__ void k_mean_bias(const float* __restrict__ agg, const float* __restrict__ b,
                            float* __restrict__ o, int total) {
    int i = blockIdx.x * blockDim.x + threadIdx.x;
    if (i >= total) return;
    int n = i >> 7, c = i & 127;
    float v = (agg[((size_t)n * 3 + 0) * HIDC + c] +
               agg[((size_t)n * 3 + 1) * HIDC + c] +
               agg[((size_t)n * 3 + 2) * HIDC + c]) * (1.f / 3.f) + b[c];
    o[i] = v;
}

// ---------------- pooling + head ----------------
__global__ void k_pool_zero(float* __restrict__ pooled, float* __restrict__ cnts) {
    int i = blockIdx.x * blockDim.x + threadIdx.x;
    if (i < NG * HIDC) pooled[i] = 0.f;
    if (i < NG) cnts[i] = 0.f;
}

__global__ void k_pool_add(const float* __restrict__ x3, const int* __restrict__ batch,
                           float* __restrict__ pooled, float* __restrict__ cnts, int N) {
    int i = blockIdx.x * blockDim.x + threadIdx.x;
    if (i >= N * HIDC) return;
    int n = i >> 7, c = i & 127;
    int g = batch[n];
    atomicAdd(&pooled[g * HIDC + c], x3[i]);
    if (c == 0) atomicAdd(&cnts[g], 1.0f);
}

__global__ void k_head(const float* __restrict__ pooled, const float* __restrict__ cnts,
                       const float* __restrict__ Wc, const float* __restrict__ bc,
                       float* __restrict__ out) {
    __shared__ float lg[NG][NCLS];
    int tid = threadIdx.x;
    if (tid < NG * NCLS) {
        int g = tid / NCLS, c = tid % NCLS;
        float invc = 1.f / fmaxf(cnts[g], 1.f);
        float s = bc[c];
        for (int k = 0; k < HIDC; ++k)
            s = fmaf(pooled[g * HIDC + k] * invc, Wc[k * NCLS + c], s);
        lg[g][c] = s;
        out[tid] = s;                 // logits
    }
    __syncthreads();
    if (tid < NG * NCLS) {
        int g = tid / NCLS, c = tid % NCLS;
        float m = -1e30f;
        for (int j = 0; j < NCLS; ++j) m = fmaxf(m, lg[g][j]);
        float se = 0.f;
        for (int j = 0; j < NCLS; ++j) se += __expf(lg[g][j] - m);
        out[NG * NCLS + tid] = lg[g][c] - m - __logf(se);
    }
}

extern "C" void kernel_launch(void* const* d_in, const int* in_sizes, int n_in,
                              void* d_out, int out_size, void* d_ws, size_t ws_size,
                              hipStream_t stream) {
    const float* x   = (const float*)d_in[0];
    const int*   ei  = (const int*)d_in[1];
    const int*   bat = (const int*)d_in[2];
    const float* W1  = (const float*)d_in[3];
    const float* a1s = (const float*)d_in[4];
    const float* a1d = (const float*)d_in[5];
    const float* b1  = (const float*)d_in[6];
    const float* W2  = (const float*)d_in[7];
    const float* a2s = (const float*)d_in[8];
    const float* a2d = (const float*)d_in[9];
    const float* b2  = (const float*)d_in[10];
    const float* W3  = (const float*)d_in[11];
    const float* a3s = (const float*)d_in[12];
    const float* a3d = (const float*)d_in[13];
    const float* b3  = (const float*)d_in[14];
    const float* Wc  = (const float*)d_in[15];
    const float* bc  = (const float*)d_in[16];
    float* out = (float*)d_out;

    char* p = (char*)d_ws;
    auto alloc = [&](size_t bytes) -> char* {
        char* r = p; p += (bytes + 255) & ~(size_t)255; return r;
    };
    u16*   xbf    = (u16*)alloc((size_t)NPAD * FIN * 2);
    u16*   x1bf   = (u16*)alloc((size_t)NPAD * 640 * 2);
    u16*   x2bf   = (u16*)alloc((size_t)NPAD * 640 * 2);
    u16*   hbf    = (u16*)alloc((size_t)NNODES * 640 * 2);
    u16*   W1t    = (u16*)alloc((size_t)640 * FIN * 2);
    u16*   W2t    = (u16*)alloc((size_t)640 * 640 * 2);
    u16*   W3t    = (u16*)alloc((size_t)384 * 640 * 2);
    float* x1     = (float*)alloc((size_t)NNODES * 640 * 4);
    float* agg    = (float*)alloc((size_t)NNODES * 640 * 4);
    float* x3     = (float*)alloc((size_t)NNODES * HIDC * 4);
    float* als    = (float*)alloc((size_t)NNODES * NH1 * 4);
    float* ald    = (float*)alloc((size_t)NNODES * NH1 * 4);
    float* pooled = (float*)alloc(NG * HIDC * 4);
    float* cnts   = (float*)alloc(NG * 4);
    int*   offs   = (int*)alloc((NNODES + 1) * 4);
    int*   cursor = (int*)alloc(NNODES * 4);
    int*   deg    = (int*)alloc(NNODES * 4);
    int*   csr    = (int*)alloc((size_t)(NEDGES + NNODES) * 4);

    const int* srcv = ei;
    const int* dstv = ei + NEDGES;

    // CSR by destination (self-loops included)
    k_init<<<(NNODES + 255) / 256, 256, 0, stream>>>(deg, cursor, NNODES);
    k_count<<<(NEDGES + 255) / 256, 256, 0, stream>>>(dstv, deg, NEDGES);
    k_scan<<<1, 256, 0, stream>>>(deg, offs, NNODES);
    k_scatter<<<(NEDGES + NNODES + 255) / 256, 256, 0, stream>>>(srcv, dstv, offs, cursor,
                                                                 csr, NEDGES, NNODES);

    // conversions
    k_f2b4<<<(NNODES * FIN / 4 + 255) / 256, 256, 0, stream>>>((const float4*)x,
                                                               (uint2*)xbf, NNODES * FIN / 4);
    k_wt<<<(FIN * 640 + 255) / 256, 256, 0, stream>>>(W1, W1t, FIN, 640);
    k_wt<<<(640 * 640 + 255) / 256, 256, 0, stream>>>(W2, W2t, 640, 640);
    k_wt<<<(640 * 384 + 255) / 256, 256, 0, stream>>>(W3, W3t, 640, 384);

    const int MB = NPAD / 128;   // 79

    // ---- layer 1 ----
    k_gemm_mfma<<<dim3(MB, 5), 256, 0, stream>>>(xbf, W1t, hbf, NNODES, FIN, 640);
    k_alphas<<<(NNODES * NH1 + 3) / 4, 256, 0, stream>>>(hbf, a1s, a1d, als, ald,
                                                         NNODES * NH1, NH1);
    k_agg<<<NNODES * NH1, 64, 0, stream>>>(hbf, als, ald, offs, csr, agg, NH1);
    k_elu_bias2<<<(NNODES * 640 + 255) / 256, 256, 0, stream>>>(agg, b1, x1, x1bf,
                                                                NNODES * 640, 640);
    // ---- layer 2 ----
    k_gemm_mfma<<<dim3(MB, 5), 256, 0, stream>>>(x1bf, W2t, hbf, NNODES, 640, 640);
    k_alphas<<<(NNODES * NH1 + 3) / 4, 256, 0, stream>>>(hbf, a2s, a2d, als, ald,
                                                         NNODES * NH1, NH1);
    k_agg<<<NNODES * NH1, 64, 0, stream>>>(hbf, als, ald, offs, csr, agg, NH1);
    k_res_elu_bias<<<(NNODES * 640 + 255) / 256, 256, 0, stream>>>(x1, agg, b2, x2bf,
                                                                   NNODES * 640, 640);
    // ---- layer 3 ----
    k_gemm_mfma<<<dim3(MB, 3), 256, 0, stream>>>(x2bf, W3t, hbf, NNODES, 640, 384);
    k_alphas<<<(NNODES * NH3 + 3) / 4, 256, 0, stream>>>(hbf, a3s, a3d, als, ald,
                                                         NNODES * NH3, NH3);
    k_agg<<<NNODES * NH3, 64, 0, stream>>>(hbf, als, ald, offs, csr, agg, NH3);
    k_mean_bias<<<(NNODES * HIDC + 255) / 256, 256, 0, stream>>>(agg, b3, x3,
                                                                 NNODES * HIDC);
    // ---- pool + head ----
    k_pool_zero<<<(NG * HIDC + 255) / 256, 256, 0, stream>>>(pooled, cnts);
    k_pool_add<<<(NNODES * HIDC + 255) / 256, 256, 0, stream>>>(x3, bat, pooled, cnts,
                                                                NNODES);
    k_head<<<1, 640, 0, stream>>>(pooled, cnts, Wc, bc, out);
}